// Round 2
// baseline (16811.661 us; speedup 1.0000x reference)
//
#include <hip/hip_runtime.h>
#include <math.h>

#define NN 50000
#define EE 600000
#define CC 600000
#define HH 128
#define LL 3
#define GG 64
#define NCLSS 10

__device__ __forceinline__ void fma4(float4& a, float s, const float4& w) {
    a.x = fmaf(s, w.x, a.x);
    a.y = fmaf(s, w.y, a.y);
    a.z = fmaf(s, w.z, a.z);
    a.w = fmaf(s, w.w, a.w);
}

__device__ __forceinline__ float4 relu4(float4 v) {
    v.x = fmaxf(v.x, 0.f); v.y = fmaxf(v.y, 0.f);
    v.z = fmaxf(v.z, 0.f); v.w = fmaxf(v.w, 0.f);
    return v;
}

__device__ __forceinline__ float4 add4(float4 a, float4 b) {
    a.x += b.x; a.y += b.y; a.z += b.z; a.w += b.w; return a;
}

// ---------------------------------------------------------------------------
// gemm128: out[M][128] = EPI( in @ W + b ),  K = 128
//   in row r = inA[r] (+ inB[r] if inB != nullptr)
//   EPI 0: write acc
//   EPI 1: write relu(acc)
//   EPI 2: write acc, and resid[row] += relu(acc)
// block 256 threads; tile = 128 rows; thread = 8 rows x 8 cols.
// LDS: W 64KB + x-tile 64KB = 128KB (1 block/CU).
// ---------------------------------------------------------------------------
template<int EPI>
__global__ __launch_bounds__(256) void gemm128_kernel(
    const float* __restrict__ inA, const float* __restrict__ inB,
    const float* __restrict__ Wg, const float* __restrict__ bg,
    float* __restrict__ outp, float* __restrict__ residp, int M)
{
    __shared__ float4 wl[128 * 32];   // [k][col_f4]
    __shared__ float4 xl[128 * 32];   // [row][k_f4 slot] (swizzled)
    const int tid = threadIdx.x;
    const int cg = tid & 15;          // col f4 indices cg and cg+16
    const int rt = tid >> 4;          // 0..15 -> rows rt*8 .. rt*8+7

    // load W once per block
    for (int i = tid; i < 128 * 32; i += 256) wl[i] = ((const float4*)Wg)[i];
    float4 b0 = ((const float4*)bg)[cg];
    float4 b1 = ((const float4*)bg)[cg + 16];

    const int ntiles = (M + 127) >> 7;
    for (int t = blockIdx.x; t < ntiles; t += gridDim.x) {
        const int row0 = t << 7;
        __syncthreads();
        // stage 128 rows x 32 f4
#pragma unroll
        for (int j = 0; j < 16; ++j) {
            int f = tid + (j << 8);
            int r = f >> 5, s = f & 31;
            int gr = row0 + r; if (gr >= M) gr = M - 1;
            float4 v = ((const float4*)inA)[(size_t)gr * 32 + s];
            if (inB) v = add4(v, ((const float4*)inB)[(size_t)gr * 32 + s]);
            int ss = s ^ (((r >> 3) & 1) << 2);
            xl[(r << 5) + ss] = v;
        }
        __syncthreads();

        float4 acc[8][2];
#pragma unroll
        for (int r = 0; r < 8; ++r) { acc[r][0] = b0; acc[r][1] = b1; }

#pragma unroll 2
        for (int kc = 0; kc < 32; ++kc) {     // 4 k per chunk
            float4 wv[4][2];
#pragma unroll
            for (int j = 0; j < 4; ++j) {
                wv[j][0] = wl[(((kc << 2) + j) << 5) + cg];
                wv[j][1] = wl[(((kc << 2) + j) << 5) + cg + 16];
            }
#pragma unroll
            for (int r = 0; r < 8; ++r) {
                int row = (rt << 3) + r;
                int ss = kc ^ (((row >> 3) & 1) << 2);
                float4 xv = xl[(row << 5) + ss];
                fma4(acc[r][0], xv.x, wv[0][0]); fma4(acc[r][1], xv.x, wv[0][1]);
                fma4(acc[r][0], xv.y, wv[1][0]); fma4(acc[r][1], xv.y, wv[1][1]);
                fma4(acc[r][0], xv.z, wv[2][0]); fma4(acc[r][1], xv.z, wv[2][1]);
                fma4(acc[r][0], xv.w, wv[3][0]); fma4(acc[r][1], xv.w, wv[3][1]);
            }
        }

#pragma unroll
        for (int r = 0; r < 8; ++r) {
            int gr = row0 + (rt << 3) + r;
            if (gr < M) {
#pragma unroll
                for (int q = 0; q < 2; ++q) {
                    float4 o = acc[r][q];
                    size_t oi = (size_t)gr * 32 + cg + q * 16;
                    if (EPI == 1) o = relu4(o);
                    ((float4*)outp)[oi] = o;
                    if (EPI == 2) {
                        float4 res = ((float4*)residp)[oi];
                        ((float4*)residp)[oi] = add4(res, relu4(acc[r][q]));
                    }
                }
            }
        }
    }
}

// ---------------------------------------------------------------------------
// edge_mlp: for each row r in [0,M):
//   cat = [ xf[idx0[r*s0]], xf[idx1[r*s1]] ]  (256)
//   h   = relu(cat @ A1 + a1)                 (128)
//   wout[r] = sigmoid( h . A2 + a2 )
// K = 256 processed as two halves of 128 (A1 half restaged per tile).
// block 256; tile = 128 rows; thread = 8 rows x 8 cols.
// LDS: A-half 64KB + x-half 64KB = 128KB.
// ---------------------------------------------------------------------------
__global__ __launch_bounds__(256) void edge_mlp_kernel(
    const float* __restrict__ xf,
    const int* __restrict__ idx0, int s0,
    const int* __restrict__ idx1, int s1,
    const float* __restrict__ A1, const float* __restrict__ a1,
    const float* __restrict__ A2, const float* __restrict__ a2,
    float* __restrict__ wout, int M)
{
    __shared__ float4 al[128 * 32];
    __shared__ float4 xl[128 * 32];
    const int tid = threadIdx.x;
    const int cg = tid & 15;
    const int rt = tid >> 4;

    float4 a1v0 = ((const float4*)a1)[cg];
    float4 a1v1 = ((const float4*)a1)[cg + 16];
    float4 A2v0 = ((const float4*)A2)[cg];
    float4 A2v1 = ((const float4*)A2)[cg + 16];
    float a2s = *a2;

    const int ntiles = (M + 127) >> 7;
    for (int t = blockIdx.x; t < ntiles; t += gridDim.x) {
        const int row0 = t << 7;
        float4 acc[8][2];
#pragma unroll
        for (int r = 0; r < 8; ++r) { acc[r][0] = a1v0; acc[r][1] = a1v1; }

        for (int half = 0; half < 2; ++half) {
            __syncthreads();
            // stage A1 half (128 k x 128 cols)
            for (int i = tid; i < 4096; i += 256)
                al[i] = ((const float4*)A1)[half * 4096 + i];
            // stage gathered x half
#pragma unroll
            for (int j = 0; j < 16; ++j) {
                int f = tid + (j << 8);
                int r = f >> 5, s = f & 31;
                int gr = row0 + r; if (gr >= M) gr = M - 1;
                int node = half ? idx1[(size_t)gr * s1] : idx0[(size_t)gr * s0];
                float4 v = ((const float4*)xf)[(size_t)node * 32 + s];
                int ss = s ^ (((r >> 3) & 1) << 2);
                xl[(r << 5) + ss] = v;
            }
            __syncthreads();

#pragma unroll 2
            for (int kc = 0; kc < 32; ++kc) {
                float4 wv[4][2];
#pragma unroll
                for (int j = 0; j < 4; ++j) {
                    wv[j][0] = al[(((kc << 2) + j) << 5) + cg];
                    wv[j][1] = al[(((kc << 2) + j) << 5) + cg + 16];
                }
#pragma unroll
                for (int r = 0; r < 8; ++r) {
                    int row = (rt << 3) + r;
                    int ss = kc ^ (((row >> 3) & 1) << 2);
                    float4 xv = xl[(row << 5) + ss];
                    fma4(acc[r][0], xv.x, wv[0][0]); fma4(acc[r][1], xv.x, wv[0][1]);
                    fma4(acc[r][0], xv.y, wv[1][0]); fma4(acc[r][1], xv.y, wv[1][1]);
                    fma4(acc[r][0], xv.z, wv[2][0]); fma4(acc[r][1], xv.z, wv[2][1]);
                    fma4(acc[r][0], xv.w, wv[3][0]); fma4(acc[r][1], xv.w, wv[3][1]);
                }
            }
        }

        // epilogue: p = relu(h) . A2, reduce over 16 lanes (col groups)
#pragma unroll
        for (int r = 0; r < 8; ++r) {
            float4 h0 = relu4(acc[r][0]);
            float4 h1 = relu4(acc[r][1]);
            float p = h0.x * A2v0.x + h0.y * A2v0.y + h0.z * A2v0.z + h0.w * A2v0.w
                    + h1.x * A2v1.x + h1.y * A2v1.y + h1.z * A2v1.z + h1.w * A2v1.w;
            p += __shfl_xor(p, 1, 16);
            p += __shfl_xor(p, 2, 16);
            p += __shfl_xor(p, 4, 16);
            p += __shfl_xor(p, 8, 16);
            if (cg == 0) {
                int gr = row0 + (rt << 3) + r;
                if (gr < M) wout[gr] = 1.f / (1.f + expf(-(p + a2s)));
            }
        }
    }
}

// ---------------------------------------------------------------------------
// msg_agg: for e in [0,M): m = relu(xsrc[i0[e]] + evec_row) * wmul[e];
//          atomicAdd(agg[i1[e]], m)
// USE_EVEC: evec is per-edge row (E x 128); else evec is a const 128-vec.
// thread handles 4 cols (f4); 32 threads per edge.
// ---------------------------------------------------------------------------
template<bool USE_EVEC>
__global__ __launch_bounds__(256) void msg_agg_kernel(
    const float* __restrict__ xsrc,
    const int* __restrict__ i0, int s0,
    const int* __restrict__ i1, int s1,
    const float* __restrict__ evec,
    const float* __restrict__ wmul,
    float* __restrict__ agg, int M)
{
    int gid = blockIdx.x * 256 + threadIdx.x;
    int e = gid >> 5;
    int c = gid & 31;
    if (e >= M) return;
    int n0 = i0[(size_t)e * s0];
    int n1 = i1[(size_t)e * s1];
    float w = wmul[e];
    float4 xv = ((const float4*)xsrc)[(size_t)n0 * 32 + c];
    float4 ev = USE_EVEC ? ((const float4*)evec)[(size_t)e * 32 + c]
                         : ((const float4*)evec)[c];
    float4 m;
    m.x = fmaxf(xv.x + ev.x, 0.f) * w;
    m.y = fmaxf(xv.y + ev.y, 0.f) * w;
    m.z = fmaxf(xv.z + ev.z, 0.f) * w;
    m.w = fmaxf(xv.w + ev.w, 0.f) * w;
    float* dst = agg + (size_t)n1 * 128 + c * 4;
    atomicAdd(dst + 0, m.x);
    atomicAdd(dst + 1, m.y);
    atomicAdd(dst + 2, m.z);
    atomicAdd(dst + 3, m.w);
}

// ---------------------------------------------------------------------------
__global__ __launch_bounds__(256) void pool_kernel(
    const float* __restrict__ xd, const int* __restrict__ batch,
    float* __restrict__ pooled, float* __restrict__ counts)
{
    int gid = blockIdx.x * 256 + threadIdx.x;
    int n = gid >> 5;
    int c = gid & 31;
    if (n >= NN) return;
    int g = batch[n];
    float4 v = ((const float4*)xd)[(size_t)n * 32 + c];
    float* dst = pooled + (size_t)g * 128 + c * 4;
    atomicAdd(dst + 0, v.x);
    atomicAdd(dst + 1, v.y);
    atomicAdd(dst + 2, v.z);
    atomicAdd(dst + 3, v.w);
    if (c == 0) atomicAdd(&counts[g], 1.0f);
}

__global__ __launch_bounds__(256) void final_kernel(
    const float* __restrict__ pooled, const float* __restrict__ counts,
    const float* __restrict__ Wf, const float* __restrict__ bf,
    float* __restrict__ outp)
{
    int gid = blockIdx.x * 256 + threadIdx.x;
    if (gid >= GG * NCLSS) return;
    int g = gid / NCLSS, cls = gid % NCLSS;
    float cnt = fmaxf(counts[g], 1.f);
    float s = 0.f;
    for (int h = 0; h < HH; ++h) s += pooled[g * HH + h] * Wf[h * NCLSS + cls];
    outp[gid] = s / cnt + bf[cls];
}

// ---------------------------------------------------------------------------
extern "C" void kernel_launch(void* const* d_in, const int* in_sizes, int n_in,
                              void* d_out, int out_size, void* d_ws, size_t ws_size,
                              hipStream_t stream)
{
    const float* x          = (const float*)d_in[0];
    const float* edge_attr  = (const float*)d_in[1];
    const float* edge_weight= (const float*)d_in[2];
    const int*   edge_index = (const int*)d_in[3];
    const int*   ecand      = (const int*)d_in[4];
    const int*   batch      = (const int*)d_in[5];
    const float* We         = (const float*)d_in[6];
    const float* be         = (const float*)d_in[7];
    const float* conv_W1    = (const float*)d_in[8];
    const float* conv_b1    = (const float*)d_in[9];
    const float* conv_W2    = (const float*)d_in[10];
    const float* conv_b2    = (const float*)d_in[11];
    const float* add_A1     = (const float*)d_in[12];
    const float* add_a1     = (const float*)d_in[13];
    const float* add_A2     = (const float*)d_in[14];
    const float* add_a2     = (const float*)d_in[15];
    const float* del_A1     = (const float*)d_in[16];
    const float* del_a1     = (const float*)d_in[17];
    const float* del_A2     = (const float*)d_in[18];
    const float* del_a2     = (const float*)d_in[19];
    const float* int_W1     = (const float*)d_in[20];
    const float* int_b1     = (const float*)d_in[21];
    const float* int_W2     = (const float*)d_in[22];
    const float* int_b2     = (const float*)d_in[23];
    const float* Wf         = (const float*)d_in[24];
    const float* bff        = (const float*)d_in[25];
    float* out = (float*)d_out;

    float* ws     = (float*)d_ws;
    float* e_emb  = ws;
    float* x_up   = e_emb + (size_t)EE * HH;
    float* x_dn   = x_up  + (size_t)NN * HH;
    float* x_new  = x_dn  + (size_t)NN * HH;
    float* aggb   = x_new + (size_t)NN * HH;
    float* tmp    = aggb  + (size_t)NN * HH;
    float* w_add  = tmp   + (size_t)NN * HH;
    float* w_keep = w_add + CC;
    float* pooled = w_keep + EE;
    float* counts = pooled + (size_t)GG * HH;

    const int* src = edge_index;
    const int* dst = edge_index + EE;
    const int* c0  = ecand;
    const int* c1  = ecand + 1;

    hipMemcpyAsync(x_up, x, (size_t)NN * HH * 4, hipMemcpyDeviceToDevice, stream);
    hipMemcpyAsync(x_dn, x, (size_t)NN * HH * 4, hipMemcpyDeviceToDevice, stream);

    const int gridE  = 2048;                 // grid-stride over 4688 tiles
    const int gridN  = (NN + 127) / 128;     // 391 tiles
    const int gridMsgE = (EE * 32) / 256;    // 75000
    const int gridMsgC = (CC * 32) / 256;
    const int gridPool = (NN * 32 + 255) / 256;

    // e_emb = edge_attr @ We + be
    gemm128_kernel<0><<<gridE, 256, 0, stream>>>(edge_attr, nullptr, We, be, e_emb, nullptr, EE);

    for (int i = 0; i < LL; ++i) {
        hipMemsetAsync(aggb, 0, (size_t)NN * HH * 4, stream);
        msg_agg_kernel<true><<<gridMsgE, 256, 0, stream>>>(
            x_up, src, 1, dst, 1, e_emb, edge_weight, aggb, EE);
        gemm128_kernel<1><<<gridN, 256, 0, stream>>>(
            x_up, aggb, conv_W1 + (size_t)i * HH * HH, conv_b1 + (size_t)i * HH, tmp, nullptr, NN);
        gemm128_kernel<2><<<gridN, 256, 0, stream>>>(
            tmp, nullptr, conv_W2 + (size_t)i * HH * HH, conv_b2 + (size_t)i * HH, x_new, x_up, NN);
        edge_mlp_kernel<<<2048, 256, 0, stream>>>(
            x_new, c0, 2, c1, 2,
            add_A1 + (size_t)i * 2 * HH * HH, add_a1 + (size_t)i * HH,
            add_A2 + (size_t)i * HH, add_a2 + i, w_add, CC);
        edge_mlp_kernel<<<2048, 256, 0, stream>>>(
            x_new, src, 1, dst, 1,
            del_A1 + (size_t)i * 2 * HH * HH, del_a1 + (size_t)i * HH,
            del_A2 + (size_t)i * HH, del_a2 + i, w_keep, EE);
        hipMemsetAsync(aggb, 0, (size_t)NN * HH * 4, stream);
        msg_agg_kernel<true><<<gridMsgE, 256, 0, stream>>>(
            x_dn, src, 1, dst, 1, e_emb, w_keep, aggb, EE);
        msg_agg_kernel<false><<<gridMsgC, 256, 0, stream>>>(
            x_dn, c0, 2, c1, 2, be, w_add, aggb, CC);
        gemm128_kernel<1><<<gridN, 256, 0, stream>>>(
            x_dn, aggb, int_W1 + (size_t)i * HH * HH, int_b1 + (size_t)i * HH, tmp, nullptr, NN);
        gemm128_kernel<2><<<gridN, 256, 0, stream>>>(
            tmp, nullptr, int_W2 + (size_t)i * HH * HH, int_b2 + (size_t)i * HH, x_new, x_dn, NN);
    }

    hipMemsetAsync(pooled, 0, ((size_t)GG * HH + GG) * 4, stream);
    pool_kernel<<<gridPool, 256, 0, stream>>>(x_dn, batch, pooled, counts);
    final_kernel<<<3, 256, 0, stream>>>(pooled, counts, Wf, bff, out);
}

// Round 5
// 3766.804 us; speedup vs baseline: 4.4631x; 4.4631x over previous
//
#include <hip/hip_runtime.h>
#include <math.h>

#define NN 50000
#define EE 600000
#define CC 600000
#define HH 128
#define LL 3
#define GG 64
#define NCLSS 10

typedef unsigned short u16;
typedef __attribute__((ext_vector_type(8))) short bf16x8;
typedef __attribute__((ext_vector_type(4))) float f32x4;

__device__ __forceinline__ u16 f2bf(float f) {
    unsigned int u = __float_as_uint(f);
    unsigned int r = (u + 0x7FFFu + ((u >> 16) & 1u)) >> 16;   // RNE
    return (u16)r;
}

__device__ __forceinline__ void fma4(float4& a, float s, const float4& w) {
    a.x = fmaf(s, w.x, a.x);
    a.y = fmaf(s, w.y, a.y);
    a.z = fmaf(s, w.z, a.z);
    a.w = fmaf(s, w.w, a.w);
}
__device__ __forceinline__ float4 relu4(float4 v) {
    v.x = fmaxf(v.x, 0.f); v.y = fmaxf(v.y, 0.f);
    v.z = fmaxf(v.z, 0.f); v.w = fmaxf(v.w, 0.f);
    return v;
}
__device__ __forceinline__ float4 add4(float4 a, float4 b) {
    a.x += b.x; a.y += b.y; a.z += b.z; a.w += b.w; return a;
}

// ---------------------------------------------------------------------------
// gemm128 v2: out[M][128] = EPI(in @ W + b), K=128 processed in 2 halves.
// LDS = 32KB W-half + 32KB x-half = 64KB -> 2 blocks/CU (8 waves).
// block 256; tile 128 rows; thread = 8 rows x 8 cols.
// ---------------------------------------------------------------------------
template<int EPI>
__global__ __launch_bounds__(256) void gemm128_kernel(
    const float* __restrict__ inA, const float* __restrict__ inB,
    const float* __restrict__ Wg, const float* __restrict__ bg,
    float* __restrict__ outp, float* __restrict__ residp, int M)
{
    __shared__ float4 wl[64 * 32];    // [k-half][col_f4] 32KB
    __shared__ float4 xl[128 * 16];   // [row][slot] swizzled 32KB
    const int tid = threadIdx.x;
    const int cg = tid & 15;          // col f4: cg and cg+16
    const int rt = tid >> 4;          // rows rt*8 .. rt*8+7

    float4 b0 = ((const float4*)bg)[cg];
    float4 b1 = ((const float4*)bg)[cg + 16];

    const int ntiles = (M + 127) >> 7;
    for (int t = blockIdx.x; t < ntiles; t += gridDim.x) {
        const int row0 = t << 7;
        float4 acc[8][2];
#pragma unroll
        for (int r = 0; r < 8; ++r) { acc[r][0] = b0; acc[r][1] = b1; }

        for (int kh = 0; kh < 2; ++kh) {
            __syncthreads();
            // stage W half: 64 k x 32 f4
#pragma unroll
            for (int j = 0; j < 8; ++j) {
                int i = tid + (j << 8);
                int k = i >> 5, c = i & 31;
                wl[i] = ((const float4*)Wg)[(size_t)(kh * 64 + k) * 32 + c];
            }
            // stage x half: 128 rows x 16 f4, swizzled
#pragma unroll
            for (int j = 0; j < 8; ++j) {
                int i = tid + (j << 8);
                int r = i >> 4, s = i & 15;
                int gr = row0 + r; if (gr >= M) gr = M - 1;
                float4 v = ((const float4*)inA)[(size_t)gr * 32 + kh * 16 + s];
                if (inB) v = add4(v, ((const float4*)inB)[(size_t)gr * 32 + kh * 16 + s]);
                xl[(r << 4) + (s ^ (r & 15))] = v;
            }
            __syncthreads();

#pragma unroll 2
            for (int kc = 0; kc < 16; ++kc) {   // 4 k per chunk
                float4 wv[4][2];
#pragma unroll
                for (int j = 0; j < 4; ++j) {
                    wv[j][0] = wl[(((kc << 2) + j) << 5) + cg];
                    wv[j][1] = wl[(((kc << 2) + j) << 5) + cg + 16];
                }
#pragma unroll
                for (int r = 0; r < 8; ++r) {
                    int row = (rt << 3) + r;
                    float4 xv = xl[(row << 4) + (kc ^ (row & 15))];
                    fma4(acc[r][0], xv.x, wv[0][0]); fma4(acc[r][1], xv.x, wv[0][1]);
                    fma4(acc[r][0], xv.y, wv[1][0]); fma4(acc[r][1], xv.y, wv[1][1]);
                    fma4(acc[r][0], xv.z, wv[2][0]); fma4(acc[r][1], xv.z, wv[2][1]);
                    fma4(acc[r][0], xv.w, wv[3][0]); fma4(acc[r][1], xv.w, wv[3][1]);
                }
            }
        }

#pragma unroll
        for (int r = 0; r < 8; ++r) {
            int gr = row0 + (rt << 3) + r;
            if (gr < M) {
#pragma unroll
                for (int q = 0; q < 2; ++q) {
                    float4 o = acc[r][q];
                    size_t oi = (size_t)gr * 32 + cg + q * 16;
                    if (EPI == 1) o = relu4(o);
                    ((float4*)outp)[oi] = o;
                    if (EPI == 2) {
                        float4 res = ((float4*)residp)[oi];
                        ((float4*)residp)[oi] = add4(res, relu4(acc[r][q]));
                    }
                }
            }
        }
    }
}

// ---------------------------------------------------------------------------
// Weight convert+transpose: A1 [256 k][128 n] f32 -> Wt [128 n][256 k] bf16
// ---------------------------------------------------------------------------
__global__ __launch_bounds__(256) void cvt_w_kernel(
    const float* __restrict__ A1, u16* __restrict__ Wt)
{
    int i = blockIdx.x * 256 + threadIdx.x;   // 32768
    int n = i >> 8, k = i & 255;
    Wt[(size_t)n * 256 + k] = f2bf(A1[(size_t)k * 128 + n]);
}

// x_new f32 -> xb bf16 (packed uint2 stores)
__global__ __launch_bounds__(256) void cvt_x_kernel(
    const float* __restrict__ xf, u16* __restrict__ xb)
{
    int i = blockIdx.x * 256 + threadIdx.x;   // NN*32
    if (i < NN * 32) {
        float4 v = ((const float4*)xf)[i];
        unsigned int lo = (unsigned int)f2bf(v.x) | ((unsigned int)f2bf(v.y) << 16);
        unsigned int hi = (unsigned int)f2bf(v.z) | ((unsigned int)f2bf(v.w) << 16);
        ((uint2*)xb)[i] = make_uint2(lo, hi);
    }
}

// ---------------------------------------------------------------------------
// edge_mlp_mfma: wout[r] = sigmoid( relu([xb[i0],xb[i1]] @ A1 + a1) . A2 + a2 )
// bf16 MFMA 16x16x32, fp32 accum. block 256 = 4 waves (2x2).
// LDS: xl 32KB + wl 32KB + pl 1KB -> 2 blocks/CU.
// ---------------------------------------------------------------------------
__global__ __launch_bounds__(256) void edge_mlp_mfma_kernel(
    const u16* __restrict__ xb,
    const int* __restrict__ idx0, int s0,
    const int* __restrict__ idx1, int s1,
    const u16* __restrict__ Wt,            // [128 col][256 k] bf16
    const float* __restrict__ a1,
    const float* __restrict__ A2, const float* __restrict__ a2,
    float* __restrict__ wout, int M)
{
    __shared__ u16 xl[16384];   // [128 row][128 k-half], 16B-unit XOR swizzle
    __shared__ u16 wl[16384];   // [128 col][128 k-half]
    __shared__ float pl[2][128];

    const int tid = threadIdx.x;
    const int l   = tid & 63;
    const int wv  = tid >> 6;
    const int wr  = wv >> 1;    // row half (0/1)
    const int wc  = wv & 1;     // col half (0/1)
    const int l15 = l & 15;
    const int l4  = l >> 4;     // 0..3

    float a1v[4], A2v[4];
#pragma unroll
    for (int cf = 0; cf < 4; ++cf) {
        int col = wc * 64 + cf * 16 + l15;
        a1v[cf] = a1[col];
        A2v[cf] = A2[col];
    }
    const float a2s = *a2;

    const int ntiles = (M + 127) >> 7;
    for (int t = blockIdx.x; t < ntiles; t += gridDim.x) {
        const int row0 = t << 7;
        f32x4 acc[4][4];
#pragma unroll
        for (int rf = 0; rf < 4; ++rf)
#pragma unroll
            for (int cf = 0; cf < 4; ++cf)
                acc[rf][cf] = (f32x4){0.f, 0.f, 0.f, 0.f};

        for (int half = 0; half < 2; ++half) {
            __syncthreads();
            // stage W half: 2048 16B-units
#pragma unroll
            for (int j = 0; j < 8; ++j) {
                int u = tid + (j << 8);
                int col = u >> 4, pos = u & 15;
                bf16x8 w8 = *reinterpret_cast<const bf16x8*>(
                    Wt + (size_t)col * 256 + half * 128 + pos * 8);
                *reinterpret_cast<bf16x8*>(wl + col * 128 + ((pos ^ (col & 15)) << 3)) = w8;
            }
            // stage gathered x half
#pragma unroll
            for (int j = 0; j < 8; ++j) {
                int u = tid + (j << 8);
                int row = u >> 4, pos = u & 15;
                int gr = row0 + row; if (gr >= M) gr = M - 1;
                int node = half ? idx1[(size_t)gr * s1] : idx0[(size_t)gr * s0];
                bf16x8 v8 = *reinterpret_cast<const bf16x8*>(
                    xb + (size_t)node * 128 + pos * 8);
                *reinterpret_cast<bf16x8*>(xl + row * 128 + ((pos ^ (row & 15)) << 3)) = v8;
            }
            __syncthreads();

#pragma unroll
            for (int ks = 0; ks < 4; ++ks) {
                const int p = ks * 4 + l4;      // 16B-unit index along k
                bf16x8 af[4], bf[4];
#pragma unroll
                for (int rf = 0; rf < 4; ++rf) {
                    int row = wr * 64 + rf * 16 + l15;
                    af[rf] = *reinterpret_cast<const bf16x8*>(
                        xl + row * 128 + ((p ^ (row & 15)) << 3));
                }
#pragma unroll
                for (int cf = 0; cf < 4; ++cf) {
                    int col = wc * 64 + cf * 16 + l15;
                    bf[cf] = *reinterpret_cast<const bf16x8*>(
                        wl + col * 128 + ((p ^ (col & 15)) << 3));
                }
#pragma unroll
                for (int rf = 0; rf < 4; ++rf)
#pragma unroll
                    for (int cf = 0; cf < 4; ++cf)
                        acc[rf][cf] = __builtin_amdgcn_mfma_f32_16x16x32_bf16(
                            af[rf], bf[cf], acc[rf][cf], 0, 0, 0);
            }
        }

        // epilogue: h = relu(acc + a1), p = h.A2, reduce cols
#pragma unroll
        for (int rf = 0; rf < 4; ++rf) {
#pragma unroll
            for (int reg = 0; reg < 4; ++reg) {
                float p = 0.f;
#pragma unroll
                for (int cf = 0; cf < 4; ++cf) {
                    float h = fmaxf(acc[rf][cf][reg] + a1v[cf], 0.f);
                    p = fmaf(h, A2v[cf], p);
                }
                p += __shfl_xor(p, 1);
                p += __shfl_xor(p, 2);
                p += __shfl_xor(p, 4);
                p += __shfl_xor(p, 8);
                if (l15 == 0) pl[wc][wr * 64 + rf * 16 + l4 * 4 + reg] = p;
            }
        }
        __syncthreads();
        if (tid < 128) {
            int gr = row0 + tid;
            if (gr < M) {
                float s = pl[0][tid] + pl[1][tid] + a2s;
                wout[gr] = 1.f / (1.f + __expf(-s));
            }
        }
    }
}

// ---------------------------------------------------------------------------
// CSR build: count -> scan -> scatter
// ---------------------------------------------------------------------------
__global__ __launch_bounds__(256) void count_kernel(
    const int* __restrict__ key, int stride, int* __restrict__ deg, int M)
{
    int e = blockIdx.x * 256 + threadIdx.x;
    if (e < M) atomicAdd(&deg[key[(size_t)e * stride]], 1);
}

__global__ __launch_bounds__(1024) void scan1_kernel(
    const int* __restrict__ deg, int* __restrict__ incl, int* __restrict__ bsum, int n)
{
    __shared__ int sd[1024];
    int tid = threadIdx.x;
    int i = blockIdx.x * 1024 + tid;
    sd[tid] = (i < n) ? deg[i] : 0;
    __syncthreads();
    for (int off = 1; off < 1024; off <<= 1) {
        int tv = (tid >= off) ? sd[tid - off] : 0;
        __syncthreads();
        sd[tid] += tv;
        __syncthreads();
    }
    if (i < n) incl[i] = sd[tid];
    if (tid == 1023) bsum[blockIdx.x] = sd[1023];
}

__global__ void scan2_kernel(int* bsum, int nb)
{
    if (threadIdx.x == 0 && blockIdx.x == 0) {
        int run = 0;
        for (int b = 0; b < nb; ++b) { int v = bsum[b]; bsum[b] = run; run += v; }
    }
}

__global__ __launch_bounds__(256) void scan3_kernel(
    const int* __restrict__ deg, const int* __restrict__ incl,
    const int* __restrict__ bsum, int* __restrict__ offs, int* __restrict__ cur,
    int n, int total)
{
    int i = blockIdx.x * 256 + threadIdx.x;
    if (i < n) {
        int ex = incl[i] - deg[i] + bsum[i >> 10];
        offs[i] = ex;
        cur[i] = ex;
    }
    if (i == 0) offs[n] = total;
}

__global__ __launch_bounds__(256) void scatter_kernel(
    const int* __restrict__ key, int stride, int* __restrict__ cur,
    int* __restrict__ eid, int M)
{
    int e = blockIdx.x * 256 + threadIdx.x;
    if (e < M) {
        int p = atomicAdd(&cur[key[(size_t)e * stride]], 1);
        eid[p] = e;
    }
}

// ---------------------------------------------------------------------------
// agg over CSR: one wave per node, lane owns 2 cols. Non-atomic write.
// ---------------------------------------------------------------------------
__global__ __launch_bounds__(256) void agg_edges_kernel(
    const float* __restrict__ xsrc, const float* __restrict__ eemb,
    const float* __restrict__ wmul, const int* __restrict__ offs,
    const int* __restrict__ eid, const int* __restrict__ srcI,
    float* __restrict__ out)
{
    int node = (blockIdx.x * 256 + threadIdx.x) >> 6;
    int l = threadIdx.x & 63;
    if (node >= NN) return;
    int j0 = offs[node], j1 = offs[node + 1];
    float2 acc = make_float2(0.f, 0.f);
    for (int j = j0; j < j1; ++j) {
        int e = eid[j];
        int s = srcI[e];
        float w = wmul[e];
        float2 xv = ((const float2*)xsrc)[(size_t)s * 64 + l];
        float2 ev = ((const float2*)eemb)[(size_t)e * 64 + l];
        acc.x += fmaxf(xv.x + ev.x, 0.f) * w;
        acc.y += fmaxf(xv.y + ev.y, 0.f) * w;
    }
    ((float2*)out)[(size_t)node * 64 + l] = acc;
}

__global__ __launch_bounds__(256) void agg_cand_kernel(
    const float* __restrict__ xsrc, const float* __restrict__ bev,
    const float* __restrict__ wmul, const int* __restrict__ offs,
    const int* __restrict__ eid, const int* __restrict__ c0,
    float* __restrict__ out)
{
    int node = (blockIdx.x * 256 + threadIdx.x) >> 6;
    int l = threadIdx.x & 63;
    if (node >= NN) return;
    float2 b = ((const float2*)bev)[l];
    int j0 = offs[node], j1 = offs[node + 1];
    float2 acc = make_float2(0.f, 0.f);
    for (int j = j0; j < j1; ++j) {
        int e = eid[j];
        int s = c0[(size_t)e * 2];
        float w = wmul[e];
        float2 xv = ((const float2*)xsrc)[(size_t)s * 64 + l];
        acc.x += fmaxf(xv.x + b.x, 0.f) * w;
        acc.y += fmaxf(xv.y + b.y, 0.f) * w;
    }
    float2 o = ((float2*)out)[(size_t)node * 64 + l];
    o.x += acc.x; o.y += acc.y;
    ((float2*)out)[(size_t)node * 64 + l] = o;
}

// ---------------------------------------------------------------------------
__global__ __launch_bounds__(256) void pool_kernel(
    const float* __restrict__ xd, const int* __restrict__ batch,
    float* __restrict__ pooled, float* __restrict__ counts)
{
    int gid = blockIdx.x * 256 + threadIdx.x;
    int n = gid >> 5;
    int c = gid & 31;
    if (n >= NN) return;
    int g = batch[n];
    float4 v = ((const float4*)xd)[(size_t)n * 32 + c];
    float* dst = pooled + (size_t)g * 128 + c * 4;
    atomicAdd(dst + 0, v.x);
    atomicAdd(dst + 1, v.y);
    atomicAdd(dst + 2, v.z);
    atomicAdd(dst + 3, v.w);
    if (c == 0) atomicAdd(&counts[g], 1.0f);
}

__global__ __launch_bounds__(256) void final_kernel(
    const float* __restrict__ pooled, const float* __restrict__ counts,
    const float* __restrict__ Wf, const float* __restrict__ bf,
    float* __restrict__ outp)
{
    int gid = blockIdx.x * 256 + threadIdx.x;
    if (gid >= GG * NCLSS) return;
    int g = gid / NCLSS, cls = gid % NCLSS;
    float cnt = fmaxf(counts[g], 1.f);
    float s = 0.f;
    for (int h = 0; h < HH; ++h) s += pooled[g * HH + h] * Wf[h * NCLSS + cls];
    outp[gid] = s / cnt + bf[cls];
}

// ---------------------------------------------------------------------------
extern "C" void kernel_launch(void* const* d_in, const int* in_sizes, int n_in,
                              void* d_out, int out_size, void* d_ws, size_t ws_size,
                              hipStream_t stream)
{
    const float* x          = (const float*)d_in[0];
    const float* edge_attr  = (const float*)d_in[1];
    const float* edge_weight= (const float*)d_in[2];
    const int*   edge_index = (const int*)d_in[3];
    const int*   ecand      = (const int*)d_in[4];
    const int*   batch      = (const int*)d_in[5];
    const float* We         = (const float*)d_in[6];
    const float* be         = (const float*)d_in[7];
    const float* conv_W1    = (const float*)d_in[8];
    const float* conv_b1    = (const float*)d_in[9];
    const float* conv_W2    = (const float*)d_in[10];
    const float* conv_b2    = (const float*)d_in[11];
    const float* add_A1     = (const float*)d_in[12];
    const float* add_a1     = (const float*)d_in[13];
    const float* add_A2     = (const float*)d_in[14];
    const float* add_a2     = (const float*)d_in[15];
    const float* del_A1     = (const float*)d_in[16];
    const float* del_a1     = (const float*)d_in[17];
    const float* del_A2     = (const float*)d_in[18];
    const float* del_a2     = (const float*)d_in[19];
    const float* int_W1     = (const float*)d_in[20];
    const float* int_b1     = (const float*)d_in[21];
    const float* int_W2     = (const float*)d_in[22];
    const float* int_b2     = (const float*)d_in[23];
    const float* Wf         = (const float*)d_in[24];
    const float* bff        = (const float*)d_in[25];
    float* out = (float*)d_out;

    float* ws     = (float*)d_ws;
    float* e_emb  = ws;
    float* x_up   = e_emb + (size_t)EE * HH;
    float* x_dn   = x_up  + (size_t)NN * HH;
    float* x_new  = x_dn  + (size_t)NN * HH;
    float* aggb   = x_new + (size_t)NN * HH;
    float* tmp    = aggb  + (size_t)NN * HH;
    float* w_add  = tmp   + (size_t)NN * HH;
    float* w_keep = w_add + CC;
    float* pooled = w_keep + EE;
    float* counts = pooled + (size_t)GG * HH;
    u16*   xb     = (u16*)(counts + GG);                 // NN*128 bf16
    u16*   wb     = xb + (size_t)NN * HH;                // 6 * 32768 bf16
    int*   ip     = (int*)(wb + 6 * 32768);
    int*   deg_d  = ip;            ip += NN;
    int*   scantmp= ip;            ip += NN;
    int*   offs_d = ip;            ip += NN + 1;
    int*   cur_d  = ip;            ip += NN;
    int*   eid_d  = ip;            ip += EE;
    int*   deg_c  = ip;            ip += NN;
    int*   offs_c = ip;            ip += NN + 1;
    int*   cur_c  = ip;            ip += NN;
    int*   eid_c  = ip;            ip += CC;
    int*   bsum   = ip;            ip += 64;

    const int* src = edge_index;
    const int* dst = edge_index + EE;
    const int* c0  = ecand;
    const int* c1  = ecand + 1;

    hipMemcpyAsync(x_up, x, (size_t)NN * HH * 4, hipMemcpyDeviceToDevice, stream);
    hipMemcpyAsync(x_dn, x, (size_t)NN * HH * 4, hipMemcpyDeviceToDevice, stream);

    const int gridE   = 2048;
    const int gridN   = (NN + 127) / 128;       // 391
    const int gridCnt = (EE + 255) / 256;       // 2344
    const int gridAgg = (NN * 64) / 256;        // 12500
    const int gridPool= (NN * 32 + 255) / 256;
    const int nbScan  = (NN + 1023) / 1024;     // 49
    const int gridS3  = (NN + 255) / 256;

    // ---- weight conversions (bf16, transposed) ----
    for (int i = 0; i < LL; ++i) {
        cvt_w_kernel<<<128, 256, 0, stream>>>(add_A1 + (size_t)i * 2 * HH * HH, wb + (size_t)(2 * i) * 32768);
        cvt_w_kernel<<<128, 256, 0, stream>>>(del_A1 + (size_t)i * 2 * HH * HH, wb + (size_t)(2 * i + 1) * 32768);
    }

    // ---- CSR builds (dst and c1) ----
    hipMemsetAsync(deg_d, 0, NN * 4, stream);
    hipMemsetAsync(deg_c, 0, NN * 4, stream);
    count_kernel<<<gridCnt, 256, 0, stream>>>(dst, 1, deg_d, EE);
    scan1_kernel<<<nbScan, 1024, 0, stream>>>(deg_d, scantmp, bsum, NN);
    scan2_kernel<<<1, 64, 0, stream>>>(bsum, nbScan);
    scan3_kernel<<<gridS3, 256, 0, stream>>>(deg_d, scantmp, bsum, offs_d, cur_d, NN, EE);
    scatter_kernel<<<gridCnt, 256, 0, stream>>>(dst, 1, cur_d, eid_d, EE);
    count_kernel<<<gridCnt, 256, 0, stream>>>(c1, 2, deg_c, CC);
    scan1_kernel<<<nbScan, 1024, 0, stream>>>(deg_c, scantmp, bsum, NN);
    scan2_kernel<<<1, 64, 0, stream>>>(bsum, nbScan);
    scan3_kernel<<<gridS3, 256, 0, stream>>>(deg_c, scantmp, bsum, offs_c, cur_c, NN, CC);
    scatter_kernel<<<gridCnt, 256, 0, stream>>>(c1, 2, cur_c, eid_c, CC);

    // ---- e_emb = edge_attr @ We + be (fp32) ----
    gemm128_kernel<0><<<gridE, 256, 0, stream>>>(edge_attr, nullptr, We, be, e_emb, nullptr, EE);

    for (int i = 0; i < LL; ++i) {
        // up-pass aggregation (CSR, writes every node -> no memset)
        agg_edges_kernel<<<gridAgg, 256, 0, stream>>>(
            x_up, e_emb, edge_weight, offs_d, eid_d, src, aggb);
        gemm128_kernel<1><<<gridN, 256, 0, stream>>>(
            x_up, aggb, conv_W1 + (size_t)i * HH * HH, conv_b1 + (size_t)i * HH, tmp, nullptr, NN);
        gemm128_kernel<2><<<gridN, 256, 0, stream>>>(
            tmp, nullptr, conv_W2 + (size_t)i * HH * HH, conv_b2 + (size_t)i * HH, x_new, x_up, NN);
        // bf16 copy of x_new for the edge MLPs
        cvt_x_kernel<<<(NN * 32 + 255) / 256, 256, 0, stream>>>(x_new, xb);
        // add / del edge MLPs (bf16 MFMA)
        edge_mlp_mfma_kernel<<<2048, 256, 0, stream>>>(
            xb, c0, 2, c1, 2, wb + (size_t)(2 * i) * 32768,
            add_a1 + (size_t)i * HH, add_A2 + (size_t)i * HH, add_a2 + i, w_add, CC);
        edge_mlp_mfma_kernel<<<2048, 256, 0, stream>>>(
            xb, src, 1, dst, 1, wb + (size_t)(2 * i + 1) * 32768,
            del_a1 + (size_t)i * HH, del_A2 + (size_t)i * HH, del_a2 + i, w_keep, EE);
        // down-pass aggregation
        agg_edges_kernel<<<gridAgg, 256, 0, stream>>>(
            x_dn, e_emb, w_keep, offs_d, eid_d, src, aggb);
        agg_cand_kernel<<<gridAgg, 256, 0, stream>>>(
            x_dn, be, w_add, offs_c, eid_c, c0, aggb);
        gemm128_kernel<1><<<gridN, 256, 0, stream>>>(
            x_dn, aggb, int_W1 + (size_t)i * HH * HH, int_b1 + (size_t)i * HH, tmp, nullptr, NN);
        gemm128_kernel<2><<<gridN, 256, 0, stream>>>(
            tmp, nullptr, int_W2 + (size_t)i * HH * HH, int_b2 + (size_t)i * HH, x_new, x_dn, NN);
    }

    hipMemsetAsync(pooled, 0, ((size_t)GG * HH + GG) * 4, stream);
    pool_kernel<<<gridPool, 256, 0, stream>>>(x_dn, batch, pooled, counts);
    final_kernel<<<3, 256, 0, stream>>>(pooled, counts, Wf, bff, out);
}